// Round 11
// baseline (389.327 us; speedup 1.0000x reference)
//
#include <hip/hip_runtime.h>
#include <hip/hip_bf16.h>
#include <cstdint>

// ---------------------------------------------------------------------------
// MLPDecoder: logit[e] = relu([zu, zv, |zu-zv|] @ W1 + b1) @ W2 + b2
//   z: [100000,128] f32, edge_index: [2,E] int, W1: [384,128], b1:[128],
//   W2: [128,1], b2:[1].  Output: [E] f32.
//
// R10: 256-thread blocks -> LDS-bound occupancy of 12 waves/CU, no reg gamble.
//   Evidence chain: R8 allocator chose 160 regs/wave (128 arch + 32 acc) ->
//   3 waves/SIMD; with 8-wave blocks that rounds down to ONE block/CU
//   (8 waves). With 4-wave blocks the same 3 waves/SIMD = 12 wave-slots/CU
//   fits THREE 48KB blocks (144 <= 160KB LDS): 12 waves/CU co-resident,
//   robust to allocator choice (cap 170 >= proven natural 160, no spill).
//   (R9's (512,4) hard 128-cap risked R3-style spill; not worth a 3rd dice
//   roll after two timeouts.)
//  - grid (384, 2): blockIdx.y = n-half; 768 blocks = exactly 3/CU.
//  - decode body identical to R8 (proven correct): W1 n-half in LDS,
//    c-group K-loop with in-place A ping-pong prefetch, butterfly epilogue,
//    atomicAdd into b2-prefilled out.
//  - prep (pack W1 + init out + cast z) fused into one kernel (launch tail
//    was a consistent 85-93us).
// ---------------------------------------------------------------------------

typedef __bf16 bf16_t;
typedef __bf16 bf16x8 __attribute__((ext_vector_type(8)));
typedef float  floatx4 __attribute__((ext_vector_type(4)));

#define DIM 128
#define E_TILE 128          // edges per block-tile (4 waves x 32 edges)
#define N_KSTEP 12          // 384 / 32
#define N_NTILE 8           // 128 / 16
#define GRID_PER_HALF 384   // 768 blocks total -> exactly 3 blocks/CU
#define PACK_BLOCKS 24      // 12*8*64 frags / 256 threads

// --- fused prep: pack W1, init out with b2, cast z fp32->bf16 ---------------
__global__ void prep_kernel(const float* __restrict__ z, bf16_t* __restrict__ zb,
                            const float* __restrict__ W1, bf16_t* __restrict__ Wp,
                            const float* __restrict__ b2, float* __restrict__ out,
                            int nfloats, int E, int init_blocks) {
    int bid = blockIdx.x;
    int tid = threadIdx.x;
    if (bid < PACK_BLOCKS) {
        // pack W1 [384,128] f32 -> MFMA B-fragment order bf16.
        // frag f = (kstep*8 + ntile); elem j of lane l:
        //   B[k = kstep*32 + (l>>4)*8 + j][n = ntile*16 + (l&15)]
        int f = bid * 256 + tid;
        if (f < N_KSTEP * N_NTILE * 64) {
            int lane = f & 63;
            int nt   = (f >> 6) & 7;
            int ks   = f >> 9;
            int n  = nt * 16 + (lane & 15);
            int k0 = ks * 32 + (lane >> 4) * 8;
            bf16x8 o;
#pragma unroll
            for (int j = 0; j < 8; ++j) o[j] = (bf16_t)W1[(k0 + j) * DIM + n];
            reinterpret_cast<bf16x8*>(Wp)[f] = o;
        }
    } else if (bid < PACK_BLOCKS + init_blocks) {
        int i = (bid - PACK_BLOCKS) * 256 + tid;
        if (i < E) out[i] = b2[0];
    } else {
        int idx = ((bid - PACK_BLOCKS - init_blocks) * 256 + tid) * 8;
        if (idx + 8 <= nfloats) {
            const float4* src = reinterpret_cast<const float4*>(z + idx);
            float4 a = src[0], b = src[1];
            bf16x8 o;
            o[0] = (bf16_t)a.x; o[1] = (bf16_t)a.y; o[2] = (bf16_t)a.z; o[3] = (bf16_t)a.w;
            o[4] = (bf16_t)b.x; o[5] = (bf16_t)b.y; o[6] = (bf16_t)b.z; o[7] = (bf16_t)b.w;
            *reinterpret_cast<bf16x8*>(zb + idx) = o;
        }
    }
}

// --- main fused kernel ------------------------------------------------------
// grid (GRID_PER_HALF, 2): blockIdx.y = n-half h. Block: 256 thr = 4 waves,
// each wave 32 edges x the block's 64 n-cols.
// __launch_bounds__(256, 3): 3 waves/EU -> cap 170 regs/wave (>= natural 160,
// no spill); LDS (48KB) then binds at 3 blocks/CU = 12 waves/CU.
template <bool PRECAST>
__global__ __launch_bounds__(256, 3)
void decode_kernel(const void* __restrict__ zsrc,
                   const int* __restrict__ ei,       // [2*E]
                   const bf16_t* __restrict__ Wp,    // packed W1 (96KB)
                   const float* __restrict__ b1,
                   const float* __restrict__ W2,
                   float* __restrict__ out, int E) {
    __shared__ __align__(16) bf16_t Bsm[N_KSTEP * 4 * 64 * 8];   // 48 KiB

    const int tid = threadIdx.x;
    const int h   = blockIdx.y;      // n-half

    // ---- stage this half of packed W1 into LDS (48KB = 3072 uint4) ----
    {
        const uint4* src = reinterpret_cast<const uint4*>(Wp);
        uint4* dst = reinterpret_cast<uint4*>(Bsm);
#pragma unroll
        for (int i = 0; i < 12; ++i) {
            int linear = i * 256 + tid;               // (ks*4+ntl)*64+lane
            int ks  = linear >> 8;
            int rem = linear & 255;                   // ntl*64+lane
            dst[linear] = src[ks * 512 + h * 256 + rem];
        }
    }
    __syncthreads();    // the only barrier in the kernel

    const int wave = tid >> 6, lane = tid & 63;      // wave = wm (0..3)
    const int l15 = lane & 15, quad = lane >> 4;

    // ---- epilogue params (this block's n-half) ----
    float b1v[4], w2v[4];
#pragma unroll
    for (int nt = 0; nt < 4; ++nt) {
        int n = (h * 4 + nt) * 16 + l15;
        b1v[nt] = b1[n];
        w2v[nt] = W2[n];
    }

    const int ntiles = (E + E_TILE - 1) / E_TILE;

    // gather one 16B chunk of zu/zv for (mt, c): cols [c*32+quad*8, +8)
    auto gatherChunk = [&](bf16x8& du, bf16x8& dv, int nu, int nv, int c) {
        if (PRECAST) {
            const bf16_t* zb = (const bf16_t*)zsrc;
            du = *reinterpret_cast<const bf16x8*>(zb + (size_t)nu * DIM + c * 32 + quad * 8);
            dv = *reinterpret_cast<const bf16x8*>(zb + (size_t)nv * DIM + c * 32 + quad * 8);
        } else {
            const float* zf = (const float*)zsrc;
            const float4* pu = reinterpret_cast<const float4*>(zf + (size_t)nu * DIM + c * 32 + quad * 8);
            const float4* pv = reinterpret_cast<const float4*>(zf + (size_t)nv * DIM + c * 32 + quad * 8);
            float4 a = pu[0], b = pu[1];
            bf16x8 o;
            o[0] = (bf16_t)a.x; o[1] = (bf16_t)a.y; o[2] = (bf16_t)a.z; o[3] = (bf16_t)a.w;
            o[4] = (bf16_t)b.x; o[5] = (bf16_t)b.y; o[6] = (bf16_t)b.z; o[7] = (bf16_t)b.w;
            du = o;
            a = pv[0]; b = pv[1];
            o[0] = (bf16_t)a.x; o[1] = (bf16_t)a.y; o[2] = (bf16_t)a.z; o[3] = (bf16_t)a.w;
            o[4] = (bf16_t)b.x; o[5] = (bf16_t)b.y; o[6] = (bf16_t)b.z; o[7] = (bf16_t)b.w;
            dv = o;
        }
    };

    // load the 4 B-frags of this half for kstep ks
    auto loadB4 = [&](bf16x8* dst, int ks) {
#pragma unroll
        for (int nt = 0; nt < 4; ++nt)
            dst[nt] = *reinterpret_cast<const bf16x8*>(
                &Bsm[(size_t)((ks * 4 + nt) * 64 + lane) * 8]);
    };

    auto loadIdx = [&](int t, int mt, int& nu, int& nv) {
        int e = t * E_TILE + wave * 32 + mt * 16 + l15;
        if (e >= E) e = E - 1;                   // clamp: compute-only, store guarded
        nu = ei[e];
        nv = ei[E + e];
    };

    // ---- A-chunk ping-pong (2 chunks live at a time, 32 arch regs) ----
    struct AChunk { bf16x8 u[2], v[2]; };
    AChunk A0, A1;
    int cnu[2], cnv[2], nnu[2], nnv[2];

    // prologue: indices + chunk 0 of the first tile
#pragma unroll
    for (int mt = 0; mt < 2; ++mt) loadIdx(blockIdx.x, mt, cnu[mt], cnv[mt]);
#pragma unroll
    for (int mt = 0; mt < 2; ++mt)
        gatherChunk(A0.u[mt], A0.v[mt], cnu[mt], cnv[mt], 0);

    // ---- persistent grid-stride loop ----
    for (int t = blockIdx.x; t < ntiles; t += GRID_PER_HALF) {
        // next tile's node indices (needed by the g=3 prefetch)
#pragma unroll
        for (int mt = 0; mt < 2; ++mt) loadIdx(t + GRID_PER_HALF, mt, nnu[mt], nnv[mt]);

        floatx4 acc[2][4];
#pragma unroll
        for (int mt = 0; mt < 2; ++mt)
#pragma unroll
            for (int nt = 0; nt < 4; ++nt) acc[mt][nt] = (floatx4)0.0f;

        // 4 c-groups; group g computes ks {g, 4+g, 8+g} from CUR while
        // prefetching chunk g+1 (or next tile's chunk 0) into NXT.
#pragma unroll
        for (int g = 0; g < 4; ++g) {
            AChunk& cur = (g & 1) ? A1 : A0;
            AChunk& nxt = (g & 1) ? A0 : A1;

            // issue prefetch first; result not needed until group g+1
            if (g < 3) {
#pragma unroll
                for (int mt = 0; mt < 2; ++mt)
                    gatherChunk(nxt.u[mt], nxt.v[mt], cnu[mt], cnv[mt], g + 1);
            } else {
#pragma unroll
                for (int mt = 0; mt < 2; ++mt)
                    gatherChunk(nxt.u[mt], nxt.v[mt], nnu[mt], nnv[mt], 0);
            }

            {   // ks = g : A = zu chunk g
                bf16x8 bc[4];
                loadB4(bc, g);
#pragma unroll
                for (int mt = 0; mt < 2; ++mt)
#pragma unroll
                    for (int nt = 0; nt < 4; ++nt)
                        acc[mt][nt] = __builtin_amdgcn_mfma_f32_16x16x32_bf16(
                            cur.u[mt], bc[nt], acc[mt][nt], 0, 0, 0);
            }
            {   // ks = 4+g : A = zv chunk g
                bf16x8 bc[4];
                loadB4(bc, 4 + g);
#pragma unroll
                for (int mt = 0; mt < 2; ++mt)
#pragma unroll
                    for (int nt = 0; nt < 4; ++nt)
                        acc[mt][nt] = __builtin_amdgcn_mfma_f32_16x16x32_bf16(
                            cur.v[mt], bc[nt], acc[mt][nt], 0, 0, 0);
            }
            {   // ks = 8+g : A = |zu - zv| chunk g
                bf16x8 bc[4];
                loadB4(bc, 8 + g);
#pragma unroll
                for (int mt = 0; mt < 2; ++mt) {
                    bf16x8 u = cur.u[mt], v = cur.v[mt];
                    bf16x8 d;
#pragma unroll
                    for (int j = 0; j < 8; ++j)
                        d[j] = (bf16_t)fabsf((float)u[j] - (float)v[j]);
#pragma unroll
                    for (int nt = 0; nt < 4; ++nt)
                        acc[mt][nt] = __builtin_amdgcn_mfma_f32_16x16x32_bf16(
                            d, bc[nt], acc[mt][nt], 0, 0, 0);
                }
            }
        }
        // after g=3: A0 holds chunk 0 of tile t+GRID_PER_HALF
#pragma unroll
        for (int mt = 0; mt < 2; ++mt) { cnu[mt] = nnu[mt]; cnv[mt] = nnv[mt]; }

        // ---- epilogue: bias + relu + dot(W2-half), butterfly, atomicAdd ----
        // C/D layout: n = (h*4+nt)*16 + l15, m = quad*4 + r
#pragma unroll
        for (int mt = 0; mt < 2; ++mt)
#pragma unroll
            for (int r = 0; r < 4; ++r) {
                float s = 0.f;
#pragma unroll
                for (int nt = 0; nt < 4; ++nt) {
                    float hh = acc[mt][nt][r] + b1v[nt];
                    hh = fmaxf(hh, 0.f);
                    s += hh * w2v[nt];
                }
                s += __shfl_xor(s, 1);
                s += __shfl_xor(s, 2);
                s += __shfl_xor(s, 4);
                s += __shfl_xor(s, 8);
                if (l15 == 0) {
                    int e = t * E_TILE + wave * 32 + mt * 16 + quad * 4 + r;
                    if (e < E) atomicAdd(&out[e], s);
                }
            }
    }
}

// ---------------------------------------------------------------------------
extern "C" void kernel_launch(void* const* d_in, const int* in_sizes, int n_in,
                              void* d_out, int out_size, void* d_ws, size_t ws_size,
                              hipStream_t stream) {
    const float* z  = (const float*)d_in[0];
    const int*   ei = (const int*)d_in[1];
    const float* W1 = (const float*)d_in[2];
    const float* b1 = (const float*)d_in[3];
    const float* W2 = (const float*)d_in[4];
    const float* b2 = (const float*)d_in[5];
    float* out = (float*)d_out;

    const int E  = in_sizes[1] / 2;
    const int zn = in_sizes[0];              // floats in z

    const size_t zb_bytes = (size_t)zn * sizeof(bf16_t);
    const size_t wp_bytes = (size_t)N_KSTEP * N_NTILE * 64 * 16;  // 98304
    const bool precast = ws_size >= zb_bytes + wp_bytes;

    bf16_t* zb = (bf16_t*)d_ws;
    bf16_t* wp = precast ? (bf16_t*)((char*)d_ws + zb_bytes) : (bf16_t*)d_ws;

    const int init_blocks = (E + 255) / 256;
    const int cast_blocks = precast ? (zn / 8 + 255) / 256 : 0;

    hipLaunchKernelGGL(prep_kernel,
                       dim3(PACK_BLOCKS + init_blocks + cast_blocks), dim3(256),
                       0, stream, z, zb, W1, wp, b2, out, zn, E, init_blocks);

    if (precast) {
        hipLaunchKernelGGL((decode_kernel<true>), dim3(GRID_PER_HALF, 2), dim3(256), 0,
                           stream, (const void*)zb, ei, wp, b1, W2, out, E);
    } else {
        hipLaunchKernelGGL((decode_kernel<false>), dim3(GRID_PER_HALF, 2), dim3(256), 0,
                           stream, (const void*)z, ei, wp, b1, W2, out, E);
    }
}

// Round 15
// 175.205 us; speedup vs baseline: 2.2221x; 2.2221x over previous
//
#include <hip/hip_runtime.h>
#include <hip/hip_bf16.h>
#include <cstdint>

// ---------------------------------------------------------------------------
// MLPDecoder: logit[e] = relu([zu, zv, |zu-zv|] @ W1 + b1) @ W2 + b2
//   z: [100000,128] f32, edge_index: [2,E] int, W1: [384,128], b1:[128],
//   W2: [128,1], b2:[1].  Output: [E] f32.
//
// R11 (4th submission -- GPU timeouts r12/r13/r14; never ran):
//   R7's proven per-wave body, 1024-thread blocks -> 16 waves share ONE
//   96KB W1 LDS copy.
//   Evidence chain: R7 (8-wave block, 96KB, VGPR 88+32acc=120, no spill) =
//   108.9us best; occupancy capped at 8 waves/CU ONLY by 2x96KB > 160KB LDS.
//   R10 showed imposing reg caps below the natural allocation spills (84 arch
//   -> 130MB scratch). A 1024-thr block needs 4 waves/SIMD -> HW cap 128
//   total/wave; R7 demand 120 <= 128 -> fits WITHOUT asking the allocator to
//   shed anything. 16 waves/CU = 2x R7 TLP, per-wave code unchanged.
//  - 256 persistent blocks (1/CU); 16 waves = 8 wm x 2 wn; E_TILE 256.
//  - c-group K-loop (ks = g,4+g,8+g) with in-place A ping-pong prefetch.
//  - cross-wn reduce via parity-buffered LDS red, ONE barrier per tile.
//  - prep = pack W1 + cast z fused (tail is fixed harness overhead anyway).
// ---------------------------------------------------------------------------

typedef __bf16 bf16_t;
typedef __bf16 bf16x8 __attribute__((ext_vector_type(8)));
typedef float  floatx4 __attribute__((ext_vector_type(4)));

#define DIM 128
#define E_TILE 256          // edges per block-tile (8 wm-groups x 32 edges)
#define N_KSTEP 12          // 384 / 32
#define N_NTILE 8           // 128 / 16
#define GRID_B 256          // persistent blocks (1 per CU)
#define PACK_BLOCKS 24      // 12*8*64 frags / 256 threads

// --- fused prep: pack W1 + cast z fp32->bf16 --------------------------------
__global__ void prep_kernel(const float* __restrict__ z, bf16_t* __restrict__ zb,
                            const float* __restrict__ W1, bf16_t* __restrict__ Wp,
                            int nfloats) {
    int bid = blockIdx.x;
    int tid = threadIdx.x;
    if (bid < PACK_BLOCKS) {
        // pack W1 [384,128] f32 -> MFMA B-fragment order bf16.
        // frag f = (kstep*8 + ntile); elem j of lane l:
        //   B[k = kstep*32 + (l>>4)*8 + j][n = ntile*16 + (l&15)]
        int f = bid * 256 + tid;
        if (f < N_KSTEP * N_NTILE * 64) {
            int lane = f & 63;
            int nt   = (f >> 6) & 7;
            int ks   = f >> 9;
            int n  = nt * 16 + (lane & 15);
            int k0 = ks * 32 + (lane >> 4) * 8;
            bf16x8 o;
#pragma unroll
            for (int j = 0; j < 8; ++j) o[j] = (bf16_t)W1[(k0 + j) * DIM + n];
            reinterpret_cast<bf16x8*>(Wp)[f] = o;
        }
    } else {
        int idx = ((bid - PACK_BLOCKS) * 256 + tid) * 8;
        if (idx + 8 <= nfloats) {
            const float4* src = reinterpret_cast<const float4*>(z + idx);
            float4 a = src[0], b = src[1];
            bf16x8 o;
            o[0] = (bf16_t)a.x; o[1] = (bf16_t)a.y; o[2] = (bf16_t)a.z; o[3] = (bf16_t)a.w;
            o[4] = (bf16_t)b.x; o[5] = (bf16_t)b.y; o[6] = (bf16_t)b.z; o[7] = (bf16_t)b.w;
            *reinterpret_cast<bf16x8*>(zb + idx) = o;
        }
    }
}

// --- main fused kernel ------------------------------------------------------
// 1024 threads = 16 waves = 8 wm x 2 wn; each wave 32 edges x 64 n-cols.
// 16 waves/CU forces 4 waves/SIMD -> reg cap 128 total; body needs ~120.
template <bool PRECAST>
__global__ __launch_bounds__(1024)
void decode_kernel(const void* __restrict__ zsrc,
                   const int* __restrict__ ei,       // [2*E]
                   const bf16_t* __restrict__ Wp,    // packed W1 (96KB)
                   const float* __restrict__ b1,
                   const float* __restrict__ W2,
                   const float* __restrict__ b2,
                   float* __restrict__ out, int E) {
    __shared__ __align__(16) bf16_t Bsm[N_KSTEP * N_NTILE * 64 * 8];  // 96 KiB
    __shared__ float red[2][2][E_TILE];                               // 4 KiB

    const int tid = threadIdx.x;

    // ---- stage packed W1 into LDS, once per persistent block ----
    {
        const uint4* src = reinterpret_cast<const uint4*>(Wp);
        uint4* dst = reinterpret_cast<uint4*>(Bsm);
#pragma unroll
        for (int i = 0; i < 6; ++i)             // 6 * 1024 * 16B = 96 KiB
            dst[i * 1024 + tid] = src[i * 1024 + tid];
    }
    __syncthreads();

    const int wave = tid >> 6, lane = tid & 63;
    const int wm = wave >> 1, wn = wave & 1;    // 8 wm x 2 wn
    const int l15 = lane & 15, quad = lane >> 4;
    const float bias2 = b2[0];

    // ---- epilogue params (this wave's n-half) ----
    float b1v[4], w2v[4];
#pragma unroll
    for (int nt = 0; nt < 4; ++nt) {
        int n = (wn * 4 + nt) * 16 + l15;
        b1v[nt] = b1[n];
        w2v[nt] = W2[n];
    }

    const int ntiles = (E + E_TILE - 1) / E_TILE;

    // gather one 16B chunk of zu/zv for (mt, c): cols [c*32+quad*8, +8)
    auto gatherChunk = [&](bf16x8& du, bf16x8& dv, int nu, int nv, int c) {
        if (PRECAST) {
            const bf16_t* zb = (const bf16_t*)zsrc;
            du = *reinterpret_cast<const bf16x8*>(zb + (size_t)nu * DIM + c * 32 + quad * 8);
            dv = *reinterpret_cast<const bf16x8*>(zb + (size_t)nv * DIM + c * 32 + quad * 8);
        } else {
            const float* zf = (const float*)zsrc;
            const float4* pu = reinterpret_cast<const float4*>(zf + (size_t)nu * DIM + c * 32 + quad * 8);
            const float4* pv = reinterpret_cast<const float4*>(zf + (size_t)nv * DIM + c * 32 + quad * 8);
            float4 a = pu[0], b = pu[1];
            bf16x8 o;
            o[0] = (bf16_t)a.x; o[1] = (bf16_t)a.y; o[2] = (bf16_t)a.z; o[3] = (bf16_t)a.w;
            o[4] = (bf16_t)b.x; o[5] = (bf16_t)b.y; o[6] = (bf16_t)b.z; o[7] = (bf16_t)b.w;
            du = o;
            a = pv[0]; b = pv[1];
            o[0] = (bf16_t)a.x; o[1] = (bf16_t)a.y; o[2] = (bf16_t)a.z; o[3] = (bf16_t)a.w;
            o[4] = (bf16_t)b.x; o[5] = (bf16_t)b.y; o[6] = (bf16_t)b.z; o[7] = (bf16_t)b.w;
            dv = o;
        }
    };

    // load the 4 B-frags of this wave's n-half for kstep ks
    auto loadB4 = [&](bf16x8* dst, int ks) {
#pragma unroll
        for (int nt = 0; nt < 4; ++nt)
            dst[nt] = *reinterpret_cast<const bf16x8*>(
                &Bsm[(size_t)((ks * N_NTILE + wn * 4 + nt) * 64 + lane) * 8]);
    };

    auto loadIdx = [&](int t, int mt, int& nu, int& nv) {
        int e = t * E_TILE + wm * 32 + mt * 16 + l15;
        if (e >= E) e = E - 1;                   // clamp: harmless duplicate work
        nu = ei[e];
        nv = ei[E + e];
    };

    // ---- A-chunk ping-pong (2 chunks live at a time, 32 arch regs) ----
    struct AChunk { bf16x8 u[2], v[2]; };
    AChunk A0, A1;
    int cnu[2], cnv[2], nnu[2], nnv[2];

    // prologue: indices + chunk 0 of the first tile
#pragma unroll
    for (int mt = 0; mt < 2; ++mt) loadIdx(blockIdx.x, mt, cnu[mt], cnv[mt]);
#pragma unroll
    for (int mt = 0; mt < 2; ++mt)
        gatherChunk(A0.u[mt], A0.v[mt], cnu[mt], cnv[mt], 0);

    int p = 0;  // red parity

    // ---- persistent grid-stride loop ----
    for (int t = blockIdx.x; t < ntiles; t += GRID_B) {
        // next tile's node indices (needed by the g=3 prefetch)
#pragma unroll
        for (int mt = 0; mt < 2; ++mt) loadIdx(t + GRID_B, mt, nnu[mt], nnv[mt]);

        floatx4 acc[2][4];
#pragma unroll
        for (int mt = 0; mt < 2; ++mt)
#pragma unroll
            for (int nt = 0; nt < 4; ++nt) acc[mt][nt] = (floatx4)0.0f;

        // 4 c-groups; group g computes ks {g, 4+g, 8+g} from CUR while
        // prefetching chunk g+1 (or next tile's chunk 0) into NXT.
#pragma unroll
        for (int g = 0; g < 4; ++g) {
            AChunk& cur = (g & 1) ? A1 : A0;
            AChunk& nxt = (g & 1) ? A0 : A1;

            // issue prefetch first; result not needed until group g+1
            if (g < 3) {
#pragma unroll
                for (int mt = 0; mt < 2; ++mt)
                    gatherChunk(nxt.u[mt], nxt.v[mt], cnu[mt], cnv[mt], g + 1);
            } else {
#pragma unroll
                for (int mt = 0; mt < 2; ++mt)
                    gatherChunk(nxt.u[mt], nxt.v[mt], nnu[mt], nnv[mt], 0);
            }

            {   // ks = g : A = zu chunk g
                bf16x8 bc[4];
                loadB4(bc, g);
#pragma unroll
                for (int mt = 0; mt < 2; ++mt)
#pragma unroll
                    for (int nt = 0; nt < 4; ++nt)
                        acc[mt][nt] = __builtin_amdgcn_mfma_f32_16x16x32_bf16(
                            cur.u[mt], bc[nt], acc[mt][nt], 0, 0, 0);
            }
            {   // ks = 4+g : A = zv chunk g
                bf16x8 bc[4];
                loadB4(bc, 4 + g);
#pragma unroll
                for (int mt = 0; mt < 2; ++mt)
#pragma unroll
                    for (int nt = 0; nt < 4; ++nt)
                        acc[mt][nt] = __builtin_amdgcn_mfma_f32_16x16x32_bf16(
                            cur.v[mt], bc[nt], acc[mt][nt], 0, 0, 0);
            }
            {   // ks = 8+g : A = |zu - zv| chunk g
                bf16x8 bc[4];
                loadB4(bc, 8 + g);
#pragma unroll
                for (int mt = 0; mt < 2; ++mt) {
                    bf16x8 u = cur.u[mt], v = cur.v[mt];
                    bf16x8 d;
#pragma unroll
                    for (int j = 0; j < 8; ++j)
                        d[j] = (bf16_t)fabsf((float)u[j] - (float)v[j]);
#pragma unroll
                    for (int nt = 0; nt < 4; ++nt)
                        acc[mt][nt] = __builtin_amdgcn_mfma_f32_16x16x32_bf16(
                            d, bc[nt], acc[mt][nt], 0, 0, 0);
                }
            }
        }
        // after g=3: A0 holds chunk 0 of tile t+GRID_B
#pragma unroll
        for (int mt = 0; mt < 2; ++mt) { cnu[mt] = nnu[mt]; cnv[mt] = nnv[mt]; }

        // ---- epilogue: bias + relu + dot(W2-half), butterfly over 16 lanes ----
        // C/D layout: n = (wn*4+nt)*16 + l15, m = quad*4 + r
#pragma unroll
        for (int mt = 0; mt < 2; ++mt)
#pragma unroll
            for (int r = 0; r < 4; ++r) {
                float s = 0.f;
#pragma unroll
                for (int nt = 0; nt < 4; ++nt) {
                    float hh = acc[mt][nt][r] + b1v[nt];
                    hh = fmaxf(hh, 0.f);
                    s += hh * w2v[nt];
                }
                s += __shfl_xor(s, 1);
                s += __shfl_xor(s, 2);
                s += __shfl_xor(s, 4);
                s += __shfl_xor(s, 8);
                if (l15 == 0)
                    red[p][wn][wm * 32 + mt * 16 + quad * 4 + r] = s;
            }
        __syncthreads();    // one barrier per tile (parity buffer allows it)

        if (tid < E_TILE) {
            int e = t * E_TILE + tid;
            if (e < E) out[e] = red[p][0][tid] + red[p][1][tid] + bias2;
        }
        p ^= 1;
    }
}

// ---------------------------------------------------------------------------
extern "C" void kernel_launch(void* const* d_in, const int* in_sizes, int n_in,
                              void* d_out, int out_size, void* d_ws, size_t ws_size,
                              hipStream_t stream) {
    const float* z  = (const float*)d_in[0];
    const int*   ei = (const int*)d_in[1];
    const float* W1 = (const float*)d_in[2];
    const float* b1 = (const float*)d_in[3];
    const float* W2 = (const float*)d_in[4];
    const float* b2 = (const float*)d_in[5];
    float* out = (float*)d_out;

    const int E  = in_sizes[1] / 2;
    const int zn = in_sizes[0];              // floats in z

    const size_t zb_bytes = (size_t)zn * sizeof(bf16_t);
    const size_t wp_bytes = (size_t)N_KSTEP * N_NTILE * 64 * 16;  // 98304
    const bool precast = ws_size >= zb_bytes + wp_bytes;

    bf16_t* zb = (bf16_t*)d_ws;
    bf16_t* wp = precast ? (bf16_t*)((char*)d_ws + zb_bytes) : (bf16_t*)d_ws;

    const int cast_blocks = precast ? (zn / 8 + 255) / 256 : 0;

    hipLaunchKernelGGL(prep_kernel, dim3(PACK_BLOCKS + cast_blocks), dim3(256),
                       0, stream, z, zb, W1, wp, zn);

    if (precast) {
        hipLaunchKernelGGL((decode_kernel<true>), dim3(GRID_B), dim3(1024), 0,
                           stream, (const void*)zb, ei, wp, b1, W2, b2, out, E);
    } else {
        hipLaunchKernelGGL((decode_kernel<false>), dim3(GRID_B), dim3(1024), 0,
                           stream, (const void*)z, ei, wp, b1, W2, b2, out, E);
    }
}